// Round 5
// baseline (1576.546 us; speedup 1.0000x reference)
//
#include <hip/hip_runtime.h>
#include <hip/hip_bf16.h>

// LightGCN 3-hop propagation, 150k nodes, 4.8M edges, EMB=64.
// Round 5: CSR gather-SpMM (R4) with cheaper CSR build:
//   - interleaved int2{col,w} record: ONE 8B scattered store/edge (R4: two 4B
//     stores to separate arrays -> 451 MB write-through; predict ~halved)
//   - int4-vectorized single-block scan (4096 counts/iter)
//   - zero_cnt merged into init; hop 3 skips the dead `next` write
// Keeps dtype-adaptive flag + R3 atomic fallback + sentinel.

#define NUM_USERS 100000
#define NUM_ITEMS 50000
#define N_NODES   150000
#define EMB       64
#define N_EDGES   4800000
#define NODE_ELEMS (N_NODES * EMB)   // 9,600,000
#define U_ELEMS    (NUM_USERS * EMB) // 6,400,000
#define I_ELEMS    (NUM_ITEMS * EMB) // 3,200,000

typedef __hip_bfloat16 bf16;

// flag bit0: float arrays are bf16 (else fp32). bit1: edge_index int64 (else int32).
__global__ void detect_kernel(const unsigned short* __restrict__ u16,
                              const int* __restrict__ ei32,
                              int* __restrict__ flag)
{
    __shared__ int s_fp32, s_i32;
    if (threadIdx.x == 0) { s_fp32 = 0; s_i32 = 0; }
    __syncthreads();
    int t = threadIdx.x;
    unsigned short u = u16[t];
    int e = (u >> 7) & 0xFF;
    if (e >= 0xC0) atomicOr(&s_fp32, 1);
    if (t < 64 && ei32[2 * t + 1] != 0) atomicOr(&s_i32, 1);
    __syncthreads();
    if (t == 0) {
        int f = 0;
        if (!s_fp32) f |= 1;
        if (!s_i32)  f |= 2;
        *flag = f;
    }
}

__device__ __forceinline__ int load_row(const int* ei32, int f, size_t e) {
    return (f & 2) ? ei32[2 * e] : ei32[e];
}
__device__ __forceinline__ int load_col(const int* ei32, int f, size_t e) {
    return (f & 2) ? ei32[2 * ((size_t)N_EDGES + e)] : ei32[(size_t)N_EDGES + e];
}
__device__ __forceinline__ float load_w(const void* ew, int f, size_t e) {
    return (f & 1) ? __bfloat162float(((const bf16*)ew)[e]) : ((const float*)ew)[e];
}

// ---------- init (embeddings + passthrough + cnt zero) / finalize ----------

__global__ void init_kernel(const void* __restrict__ users,
                            const void* __restrict__ items,
                            void* __restrict__ out,
                            float* __restrict__ A,
                            float* __restrict__ B,
                            float* __restrict__ ACC,
                            int* __restrict__ cnt,
                            const int* __restrict__ flag,
                            int zeroB)
{
    int gid = blockIdx.x * blockDim.x + threadIdx.x;
    if (gid >= NODE_ELEMS) return;
    if (gid < N_NODES) cnt[gid] = 0;
    const bool isb = ((*flag) & 1);
    float v;
    if (gid < U_ELEMS) {
        if (isb) { bf16 b = ((const bf16*)users)[gid]; v = __bfloat162float(b); ((bf16*)out)[U_ELEMS + gid] = b; }
        else     { float fv = ((const float*)users)[gid]; v = fv; ((float*)out)[U_ELEMS + gid] = fv; }
    } else {
        int ii = gid - U_ELEMS;
        if (isb) { bf16 b = ((const bf16*)items)[ii]; v = __bfloat162float(b); ((bf16*)out)[2 * U_ELEMS + I_ELEMS + ii] = b; }
        else     { float fv = ((const float*)items)[ii]; v = fv; ((float*)out)[2 * U_ELEMS + I_ELEMS + ii] = fv; }
    }
    A[gid]   = v;
    if (zeroB) B[gid] = 0.0f;   // only the atomic fallback needs a zeroed target
    ACC[gid] = v;
}

__global__ void finalize_kernel(const float* __restrict__ acc,
                                void* __restrict__ out,
                                const int* __restrict__ flag)
{
    int gid = blockIdx.x * blockDim.x + threadIdx.x;
    if (gid >= NODE_ELEMS) return;
    const bool isb = ((*flag) & 1);
    float v = acc[gid] * 0.25f;
    size_t o = (gid < U_ELEMS) ? (size_t)gid : (size_t)(2 * U_ELEMS + (gid - U_ELEMS));
    if (isb) ((bf16*)out)[o]  = __float2bfloat16(v);
    else     ((float*)out)[o] = v;
}

// ---------- CSR build ----------

__global__ void hist_kernel(const int* __restrict__ ei32,
                            int* __restrict__ cnt,
                            const int* __restrict__ flag)
{
    int e = blockIdx.x * blockDim.x + threadIdx.x;
    if (e >= N_EDGES) return;
    atomicAdd(&cnt[load_row(ei32, *flag, e)], 1);
}

// single-block exclusive scan, int4-vectorized: N_NODES % 4 == 0
__global__ void scan_kernel(const int4* __restrict__ cnt4,
                            int* __restrict__ rowptr,
                            int* __restrict__ fill_off)
{
    __shared__ int ls[16];
    __shared__ int s_carry;
    const int t = threadIdx.x;          // 1024 threads = 16 waves
    const int lane = t & 63;
    const int wv = t >> 6;
    if (t == 0) s_carry = 0;
    __syncthreads();
    const int NV = N_NODES / 4;         // 37,500 int4 elements
    for (int base = 0; base < NV; base += 1024) {
        int i = base + t;
        int4 c = (i < NV) ? cnt4[i] : make_int4(0, 0, 0, 0);
        int tsum = c.x + c.y + c.z + c.w;
        int v = tsum;                    // wave inclusive scan of thread sums
        #pragma unroll
        for (int d = 1; d < 64; d <<= 1) {
            int y = __shfl_up(v, d, 64);
            if (lane >= d) v += y;
        }
        if (lane == 63) ls[wv] = v;
        __syncthreads();
        if (wv == 0 && lane < 16) {
            int s = ls[lane];
            #pragma unroll
            for (int d = 1; d < 16; d <<= 1) {
                int y = __shfl_up(s, d, 64);
                if (lane >= d) s += y;
            }
            ls[lane] = s;
        }
        __syncthreads();
        int waveoff = (wv == 0) ? 0 : ls[wv - 1];
        int carry = s_carry;
        if (i < NV) {
            int excl = carry + waveoff + v - tsum;
            int4 r;
            r.x = excl;
            r.y = r.x + c.x;
            r.z = r.y + c.y;
            r.w = r.z + c.z;
            ((int4*)rowptr)[i]   = r;
            ((int4*)fill_off)[i] = r;
        }
        __syncthreads();                 // all reads of s_carry done
        if (t == 0) s_carry = carry + ls[15];
        __syncthreads();
    }
    if (t == 0) rowptr[N_NODES] = s_carry;   // == N_EDGES
}

__global__ void fill_kernel(const int* __restrict__ ei32,
                            const void* __restrict__ ew,
                            int* __restrict__ fill_off,
                            int2* __restrict__ rec,
                            const int* __restrict__ flag)
{
    int e = blockIdx.x * blockDim.x + threadIdx.x;
    if (e >= N_EDGES) return;
    const int f = *flag;
    int row = load_row(ei32, f, e);
    int col = load_col(ei32, f, e);
    float w = load_w(ew, f, e);
    int pos = atomicAdd(&fill_off[row], 1);
    rec[pos] = make_int2(col, __float_as_int(w));   // one 8B scattered store
}

// ---------- gather-only hop: wave per row, lane = emb dim ----------

template <bool WRITE_NEXT>
__global__ void hop_kernel(const int* __restrict__ rowptr,
                           const int2* __restrict__ rec,
                           const float* __restrict__ prev,
                           float* __restrict__ next,
                           float* __restrict__ acc)
{
    int row  = blockIdx.x * (blockDim.x >> 6) + (threadIdx.x >> 6);
    int lane = threadIdx.x & 63;
    if (row >= N_NODES) return;
    int s = rowptr[row], e = rowptr[row + 1];
    float a0 = 0.0f, a1 = 0.0f;
    int k = s;
    for (; k + 1 < e; k += 2) {
        int2 r0 = rec[k];
        int2 r1 = rec[k + 1];
        a0 += __int_as_float(r0.y) * prev[(size_t)r0.x * EMB + lane];
        a1 += __int_as_float(r1.y) * prev[(size_t)r1.x * EMB + lane];
    }
    if (k < e) {
        int2 r = rec[k];
        a0 += __int_as_float(r.y) * prev[(size_t)r.x * EMB + lane];
    }
    float a = a0 + a1;
    size_t o = (size_t)row * EMB + lane;
    if (WRITE_NEXT) next[o] = a;
    acc[o] += a;
}

// ---------- R3 atomic fallback ----------

__global__ void scatter_kernel(const int* __restrict__ ei32,
                               const void* __restrict__ ew,
                               const float* __restrict__ prev,
                               float* __restrict__ next,
                               const int* __restrict__ flag)
{
    int gid = blockIdx.x * blockDim.x + threadIdx.x;
    if (gid >= N_EDGES * 16) return;
    const int f = *flag;
    int e = gid >> 4;
    int j = (gid & 15) << 2;
    int row = load_row(ei32, f, e);
    int col = load_col(ei32, f, e);
    float w = load_w(ew, f, e);
    const float4 v = *reinterpret_cast<const float4*>(prev + (size_t)col * EMB + j);
    float* dst = next + (size_t)row * EMB + j;
    unsafeAtomicAdd(dst + 0, w * v.x);
    unsafeAtomicAdd(dst + 1, w * v.y);
    unsafeAtomicAdd(dst + 2, w * v.z);
    unsafeAtomicAdd(dst + 3, w * v.w);
}

__global__ void accum_zero_kernel(float* __restrict__ acc,
                                  const float* __restrict__ next,
                                  float* __restrict__ prevz)
{
    int gid = blockIdx.x * blockDim.x + threadIdx.x;
    if (gid >= NODE_ELEMS) return;
    acc[gid] += next[gid];
    prevz[gid] = 0.0f;
}

__global__ void sentinel_kernel(unsigned int* __restrict__ out, int nwords)
{
    int gid = blockIdx.x * blockDim.x + threadIdx.x;
    if (gid < nwords) out[gid] = 0x447A447Au;
}

extern "C" void kernel_launch(void* const* d_in, const int* in_sizes, int n_in,
                              void* d_out, int out_size, void* d_ws, size_t ws_size,
                              hipStream_t stream)
{
    const void* users = d_in[0];
    const void* items = d_in[1];
    const int*  ei32  = (const int*)d_in[2];
    const void* ew    = d_in[3];

    char* wsb  = (char*)d_ws;
    int*  flag = (int*)wsb;
    float* A   = (float*)(wsb + 256);
    float* B   = A + (size_t)NODE_ELEMS;
    float* ACC = B + (size_t)NODE_ELEMS;
    char* p    = (char*)(ACC + (size_t)NODE_ELEMS);
    int*  rowptr   = (int*)p;  p += (N_NODES + 4) * sizeof(int);  // +4 keeps fill_off 16B-aligned
    int*  fill_off = (int*)p;  p += N_NODES * sizeof(int);
    int*  cnt      = (int*)p;  p += N_NODES * sizeof(int);
    int2* rec      = (int2*)p; p += (size_t)N_EDGES * sizeof(int2);

    const size_t need_csr    = (size_t)(p - wsb);                          // ~155 MB
    const size_t need_atomic = 256 + 3 * (size_t)NODE_ELEMS * sizeof(float);
    const int BLK = 256;
    const int node_blocks = (NODE_ELEMS + BLK - 1) / BLK;
    const int row_blocks  = (N_NODES + 3) / 4;              // 4 waves (rows) per block
    const int edge_blocks = (N_EDGES + BLK - 1) / BLK;

    if (ws_size >= need_csr) {
        detect_kernel<<<1, BLK, 0, stream>>>((const unsigned short*)users, ei32, flag);
        init_kernel<<<node_blocks, BLK, 0, stream>>>(users, items, d_out, A, B, ACC, cnt, flag, 0);
        hist_kernel<<<edge_blocks, BLK, 0, stream>>>(ei32, cnt, flag);
        scan_kernel<<<1, 1024, 0, stream>>>((const int4*)cnt, rowptr, fill_off);
        fill_kernel<<<edge_blocks, BLK, 0, stream>>>(ei32, ew, fill_off, rec, flag);

        hop_kernel<true ><<<row_blocks, BLK, 0, stream>>>(rowptr, rec, A, B, ACC);
        hop_kernel<true ><<<row_blocks, BLK, 0, stream>>>(rowptr, rec, B, A, ACC);
        hop_kernel<false><<<row_blocks, BLK, 0, stream>>>(rowptr, rec, A, B, ACC);

        finalize_kernel<<<node_blocks, BLK, 0, stream>>>(ACC, d_out, flag);
    } else if (ws_size >= need_atomic) {
        const int sedge_blocks = (N_EDGES * 16 + BLK - 1) / BLK;
        detect_kernel<<<1, BLK, 0, stream>>>((const unsigned short*)users, ei32, flag);
        init_kernel<<<node_blocks, BLK, 0, stream>>>(users, items, d_out, A, B, ACC, fill_off, flag, 1);
        float* prev = A;
        float* nxt  = B;
        for (int h = 0; h < 3; ++h) {
            scatter_kernel<<<sedge_blocks, BLK, 0, stream>>>(ei32, ew, prev, nxt, flag);
            accum_zero_kernel<<<node_blocks, BLK, 0, stream>>>(ACC, nxt, prev);
            float* t = prev; prev = nxt; nxt = t;
        }
        finalize_kernel<<<node_blocks, BLK, 0, stream>>>(ACC, d_out, flag);
    } else {
        int nwords = out_size / 2;
        sentinel_kernel<<<(nwords + BLK - 1) / BLK, BLK, 0, stream>>>((unsigned int*)d_out, nwords);
    }
}

// Round 6
// 1288.667 us; speedup vs baseline: 1.2234x; 1.2234x over previous
//
#include <hip/hip_runtime.h>
#include <hip/hip_bf16.h>

// LightGCN 3-hop propagation, 150k nodes, 4.8M edges, EMB=64.
// Round 6:
//  - fill reverted to R4 two-array layout (R5's int2 fill: fewer bytes but
//    SLOWER — scattered-append sector density per stream beats total volume)
//  - bf16 storage for hop intermediates when inputs are bf16 (halves gather
//    volume; ACC stays fp32), 4-deep unrolled gather loop (latency-bound)
//  - finalize fused into hop 3 (writes d_out directly)
// Keeps dtype-adaptive flag + R3 atomic fallback + sentinel.

#define NUM_USERS 100000
#define NUM_ITEMS 50000
#define N_NODES   150000
#define EMB       64
#define N_EDGES   4800000
#define NODE_ELEMS (N_NODES * EMB)   // 9,600,000
#define U_ELEMS    (NUM_USERS * EMB) // 6,400,000
#define I_ELEMS    (NUM_ITEMS * EMB) // 3,200,000

typedef __hip_bfloat16 bf16;

// flag bit0: float arrays are bf16 (else fp32). bit1: edge_index int64 (else int32).
__global__ void detect_kernel(const unsigned short* __restrict__ u16,
                              const int* __restrict__ ei32,
                              int* __restrict__ flag)
{
    __shared__ int s_fp32, s_i32;
    if (threadIdx.x == 0) { s_fp32 = 0; s_i32 = 0; }
    __syncthreads();
    int t = threadIdx.x;
    unsigned short u = u16[t];
    int e = (u >> 7) & 0xFF;
    if (e >= 0xC0) atomicOr(&s_fp32, 1);
    if (t < 64 && ei32[2 * t + 1] != 0) atomicOr(&s_i32, 1);
    __syncthreads();
    if (t == 0) {
        int f = 0;
        if (!s_fp32) f |= 1;
        if (!s_i32)  f |= 2;
        *flag = f;
    }
}

__device__ __forceinline__ int load_row(const int* ei32, int f, size_t e) {
    return (f & 2) ? ei32[2 * e] : ei32[e];
}
__device__ __forceinline__ int load_col(const int* ei32, int f, size_t e) {
    return (f & 2) ? ei32[2 * ((size_t)N_EDGES + e)] : ei32[(size_t)N_EDGES + e];
}
__device__ __forceinline__ float load_w(const void* ew, int f, size_t e) {
    return (f & 1) ? __bfloat162float(((const bf16*)ew)[e]) : ((const float*)ew)[e];
}

// ---------- init (embeddings + passthrough + cnt zero) ----------
// storage_bf16: if 1 and flag says bf16, A is stored as bf16 (CSR path);
// fallback atomic path passes 0 so scatter_kernel can read fp32.
__global__ void init_kernel(const void* __restrict__ users,
                            const void* __restrict__ items,
                            void* __restrict__ out,
                            void* __restrict__ A,
                            float* __restrict__ B,
                            float* __restrict__ ACC,
                            int* __restrict__ cnt,
                            const int* __restrict__ flag,
                            int storage_bf16,
                            int zeroB)
{
    int gid = blockIdx.x * blockDim.x + threadIdx.x;
    if (gid >= NODE_ELEMS) return;
    if (gid < N_NODES) cnt[gid] = 0;
    const bool isb = ((*flag) & 1);
    float v;
    if (gid < U_ELEMS) {
        if (isb) { bf16 b = ((const bf16*)users)[gid]; v = __bfloat162float(b); ((bf16*)out)[U_ELEMS + gid] = b; }
        else     { float fv = ((const float*)users)[gid]; v = fv; ((float*)out)[U_ELEMS + gid] = fv; }
    } else {
        int ii = gid - U_ELEMS;
        if (isb) { bf16 b = ((const bf16*)items)[ii]; v = __bfloat162float(b); ((bf16*)out)[2 * U_ELEMS + I_ELEMS + ii] = b; }
        else     { float fv = ((const float*)items)[ii]; v = fv; ((float*)out)[2 * U_ELEMS + I_ELEMS + ii] = fv; }
    }
    if (isb && storage_bf16) ((bf16*)A)[gid] = __float2bfloat16(v);
    else                     ((float*)A)[gid] = v;
    if (zeroB) B[gid] = 0.0f;   // only the atomic fallback needs a zeroed target
    ACC[gid] = v;
}

// finalize used only by the atomic fallback path (CSR path fuses into hop 3)
__global__ void finalize_kernel(const float* __restrict__ acc,
                                void* __restrict__ out,
                                const int* __restrict__ flag)
{
    int gid = blockIdx.x * blockDim.x + threadIdx.x;
    if (gid >= NODE_ELEMS) return;
    const bool isb = ((*flag) & 1);
    float v = acc[gid] * 0.25f;
    size_t o = (gid < U_ELEMS) ? (size_t)gid : (size_t)(2 * U_ELEMS + (gid - U_ELEMS));
    if (isb) ((bf16*)out)[o]  = __float2bfloat16(v);
    else     ((float*)out)[o] = v;
}

// ---------- CSR build ----------

__global__ void hist_kernel(const int* __restrict__ ei32,
                            int* __restrict__ cnt,
                            const int* __restrict__ flag)
{
    int e = blockIdx.x * blockDim.x + threadIdx.x;
    if (e >= N_EDGES) return;
    atomicAdd(&cnt[load_row(ei32, *flag, e)], 1);
}

// single-block exclusive scan, int4-vectorized: N_NODES % 4 == 0
__global__ void scan_kernel(const int4* __restrict__ cnt4,
                            int* __restrict__ rowptr,
                            int* __restrict__ fill_off)
{
    __shared__ int ls[16];
    __shared__ int s_carry;
    const int t = threadIdx.x;          // 1024 threads = 16 waves
    const int lane = t & 63;
    const int wv = t >> 6;
    if (t == 0) s_carry = 0;
    __syncthreads();
    const int NV = N_NODES / 4;         // 37,500 int4 elements
    for (int base = 0; base < NV; base += 1024) {
        int i = base + t;
        int4 c = (i < NV) ? cnt4[i] : make_int4(0, 0, 0, 0);
        int tsum = c.x + c.y + c.z + c.w;
        int v = tsum;
        #pragma unroll
        for (int d = 1; d < 64; d <<= 1) {
            int y = __shfl_up(v, d, 64);
            if (lane >= d) v += y;
        }
        if (lane == 63) ls[wv] = v;
        __syncthreads();
        if (wv == 0 && lane < 16) {
            int s = ls[lane];
            #pragma unroll
            for (int d = 1; d < 16; d <<= 1) {
                int y = __shfl_up(s, d, 64);
                if (lane >= d) s += y;
            }
            ls[lane] = s;
        }
        __syncthreads();
        int waveoff = (wv == 0) ? 0 : ls[wv - 1];
        int carry = s_carry;
        if (i < NV) {
            int excl = carry + waveoff + v - tsum;
            int4 r;
            r.x = excl;
            r.y = r.x + c.x;
            r.z = r.y + c.y;
            r.w = r.z + c.z;
            ((int4*)rowptr)[i]   = r;
            ((int4*)fill_off)[i] = r;
        }
        __syncthreads();
        if (t == 0) s_carry = carry + ls[15];
        __syncthreads();
    }
    if (t == 0) rowptr[N_NODES] = s_carry;   // == N_EDGES
}

// R4 two-array fill (measured faster than int2-interleaved: 315 vs 403 us)
__global__ void fill_kernel(const int* __restrict__ ei32,
                            const void* __restrict__ ew,
                            int* __restrict__ fill_off,
                            int* __restrict__ csr_col,
                            float* __restrict__ csr_w,
                            const int* __restrict__ flag)
{
    int e = blockIdx.x * blockDim.x + threadIdx.x;
    if (e >= N_EDGES) return;
    const int f = *flag;
    int row = load_row(ei32, f, e);
    int col = load_col(ei32, f, e);
    float w = load_w(ew, f, e);
    int pos = atomicAdd(&fill_off[row], 1);
    csr_col[pos] = col;
    csr_w[pos]   = w;
}

// ---------- gather-only hop: wave per row, lane = emb dim ----------
// prev/next stored bf16 when flag bit0 (halves gather volume); ACC fp32.
// LAST: fuse epilogue — write (acc+a)*0.25 straight to d_out, skip next/acc.

template <bool LAST>
__global__ void hop_kernel(const int* __restrict__ rowptr,
                           const int* __restrict__ csr_col,
                           const float* __restrict__ csr_w,
                           const void* __restrict__ prev,
                           void* __restrict__ next,
                           float* __restrict__ acc,
                           void* __restrict__ out,
                           const int* __restrict__ flag)
{
    int row  = blockIdx.x * (blockDim.x >> 6) + (threadIdx.x >> 6);
    int lane = threadIdx.x & 63;
    if (row >= N_NODES) return;
    const bool isb = ((*flag) & 1);
    int s = rowptr[row], e = rowptr[row + 1];
    float a0 = 0.f, a1 = 0.f, a2 = 0.f, a3 = 0.f;
    int k = s;
    if (isb) {
        const bf16* p = (const bf16*)prev;
        for (; k + 3 < e; k += 4) {
            int   c0 = csr_col[k], c1 = csr_col[k+1], c2 = csr_col[k+2], c3 = csr_col[k+3];
            float w0 = csr_w[k],   w1 = csr_w[k+1],   w2 = csr_w[k+2],   w3 = csr_w[k+3];
            a0 += w0 * __bfloat162float(p[(size_t)c0 * EMB + lane]);
            a1 += w1 * __bfloat162float(p[(size_t)c1 * EMB + lane]);
            a2 += w2 * __bfloat162float(p[(size_t)c2 * EMB + lane]);
            a3 += w3 * __bfloat162float(p[(size_t)c3 * EMB + lane]);
        }
        for (; k < e; ++k)
            a0 += csr_w[k] * __bfloat162float(p[(size_t)csr_col[k] * EMB + lane]);
    } else {
        const float* p = (const float*)prev;
        for (; k + 3 < e; k += 4) {
            int   c0 = csr_col[k], c1 = csr_col[k+1], c2 = csr_col[k+2], c3 = csr_col[k+3];
            float w0 = csr_w[k],   w1 = csr_w[k+1],   w2 = csr_w[k+2],   w3 = csr_w[k+3];
            a0 += w0 * p[(size_t)c0 * EMB + lane];
            a1 += w1 * p[(size_t)c1 * EMB + lane];
            a2 += w2 * p[(size_t)c2 * EMB + lane];
            a3 += w3 * p[(size_t)c3 * EMB + lane];
        }
        for (; k < e; ++k)
            a0 += csr_w[k] * p[(size_t)csr_col[k] * EMB + lane];
    }
    float a = (a0 + a1) + (a2 + a3);
    size_t o = (size_t)row * EMB + lane;
    if (LAST) {
        float v = (acc[o] + a) * 0.25f;
        size_t oo = (row < NUM_USERS) ? o : o + (size_t)U_ELEMS;  // i_final block starts at 2*U_ELEMS
        if (isb) ((bf16*)out)[oo]  = __float2bfloat16(v);
        else     ((float*)out)[oo] = v;
    } else {
        if (isb) ((bf16*)next)[o] = __float2bfloat16(a);
        else     ((float*)next)[o] = a;
        acc[o] += a;
    }
}

// ---------- R3 atomic fallback ----------

__global__ void scatter_kernel(const int* __restrict__ ei32,
                               const void* __restrict__ ew,
                               const float* __restrict__ prev,
                               float* __restrict__ next,
                               const int* __restrict__ flag)
{
    int gid = blockIdx.x * blockDim.x + threadIdx.x;
    if (gid >= N_EDGES * 16) return;
    const int f = *flag;
    int e = gid >> 4;
    int j = (gid & 15) << 2;
    int row = load_row(ei32, f, e);
    int col = load_col(ei32, f, e);
    float w = load_w(ew, f, e);
    const float4 v = *reinterpret_cast<const float4*>(prev + (size_t)col * EMB + j);
    float* dst = next + (size_t)row * EMB + j;
    unsafeAtomicAdd(dst + 0, w * v.x);
    unsafeAtomicAdd(dst + 1, w * v.y);
    unsafeAtomicAdd(dst + 2, w * v.z);
    unsafeAtomicAdd(dst + 3, w * v.w);
}

__global__ void accum_zero_kernel(float* __restrict__ acc,
                                  const float* __restrict__ next,
                                  float* __restrict__ prevz)
{
    int gid = blockIdx.x * blockDim.x + threadIdx.x;
    if (gid >= NODE_ELEMS) return;
    acc[gid] += next[gid];
    prevz[gid] = 0.0f;
}

__global__ void sentinel_kernel(unsigned int* __restrict__ out, int nwords)
{
    int gid = blockIdx.x * blockDim.x + threadIdx.x;
    if (gid < nwords) out[gid] = 0x447A447Au;
}

extern "C" void kernel_launch(void* const* d_in, const int* in_sizes, int n_in,
                              void* d_out, int out_size, void* d_ws, size_t ws_size,
                              hipStream_t stream)
{
    const void* users = d_in[0];
    const void* items = d_in[1];
    const int*  ei32  = (const int*)d_in[2];
    const void* ew    = d_in[3];

    char* wsb  = (char*)d_ws;
    int*  flag = (int*)wsb;
    float* A   = (float*)(wsb + 256);            // sized for fp32 worst case
    float* B   = A + (size_t)NODE_ELEMS;
    float* ACC = B + (size_t)NODE_ELEMS;
    char* p    = (char*)(ACC + (size_t)NODE_ELEMS);
    int*  rowptr   = (int*)p;  p += (N_NODES + 4) * sizeof(int);
    int*  fill_off = (int*)p;  p += N_NODES * sizeof(int);
    int*  cnt      = (int*)p;  p += N_NODES * sizeof(int);
    int*  csr_col  = (int*)p;  p += (size_t)N_EDGES * sizeof(int);
    float* csr_w   = (float*)p; p += (size_t)N_EDGES * sizeof(float);

    const size_t need_csr    = (size_t)(p - wsb);                          // ~155 MB
    const size_t need_atomic = 256 + 3 * (size_t)NODE_ELEMS * sizeof(float);
    const int BLK = 256;
    const int node_blocks = (NODE_ELEMS + BLK - 1) / BLK;
    const int row_blocks  = (N_NODES + 3) / 4;              // 4 waves (rows) per block
    const int edge_blocks = (N_EDGES + BLK - 1) / BLK;

    if (ws_size >= need_csr) {
        detect_kernel<<<1, BLK, 0, stream>>>((const unsigned short*)users, ei32, flag);
        init_kernel<<<node_blocks, BLK, 0, stream>>>(users, items, d_out, A, B, ACC, cnt, flag, 1, 0);
        hist_kernel<<<edge_blocks, BLK, 0, stream>>>(ei32, cnt, flag);
        scan_kernel<<<1, 1024, 0, stream>>>((const int4*)cnt, rowptr, fill_off);
        fill_kernel<<<edge_blocks, BLK, 0, stream>>>(ei32, ew, fill_off, csr_col, csr_w, flag);

        hop_kernel<false><<<row_blocks, BLK, 0, stream>>>(rowptr, csr_col, csr_w, A, B, ACC, d_out, flag);
        hop_kernel<false><<<row_blocks, BLK, 0, stream>>>(rowptr, csr_col, csr_w, B, A, ACC, d_out, flag);
        hop_kernel<true ><<<row_blocks, BLK, 0, stream>>>(rowptr, csr_col, csr_w, A, B, ACC, d_out, flag);
    } else if (ws_size >= need_atomic) {
        const int sedge_blocks = (N_EDGES * 16 + BLK - 1) / BLK;
        detect_kernel<<<1, BLK, 0, stream>>>((const unsigned short*)users, ei32, flag);
        init_kernel<<<node_blocks, BLK, 0, stream>>>(users, items, d_out, A, B, ACC, fill_off, flag, 0, 1);
        float* prev = A;
        float* nxt  = B;
        for (int h = 0; h < 3; ++h) {
            scatter_kernel<<<sedge_blocks, BLK, 0, stream>>>(ei32, ew, prev, nxt, flag);
            accum_zero_kernel<<<node_blocks, BLK, 0, stream>>>(ACC, nxt, prev);
            float* t = prev; prev = nxt; nxt = t;
        }
        finalize_kernel<<<node_blocks, BLK, 0, stream>>>(ACC, d_out, flag);
    } else {
        int nwords = out_size / 2;
        sentinel_kernel<<<(nwords + BLK - 1) / BLK, BLK, 0, stream>>>((unsigned int*)d_out, nwords);
    }
}

// Round 7
// 862.002 us; speedup vs baseline: 1.8289x; 1.4950x over previous
//
#include <hip/hip_runtime.h>
#include <hip/hip_bf16.h>

// LightGCN 3-hop propagation, 150k nodes, 4.8M edges, EMB=64.
// Round 7: binned CSR build (kills the 420us scatter-fill + global row hist/scan):
//   bucket_hist -> bucket_scan -> bin (LDS-staged, coalesced bucket runs,
//   output aliases B) -> local_fill (per-bucket L2-window scatter, emits rowptr).
// Hops: bf16 storage, unroll 8, hop1 fuses ACC=emb0+h1, hop3 fuses epilogue.
// Keeps dtype-adaptive flag + R3 atomic fallback + sentinel.

#define NUM_USERS 100000
#define NUM_ITEMS 50000
#define N_NODES   150000
#define EMB       64
#define N_EDGES   4800000
#define NODE_ELEMS (N_NODES * EMB)   // 9,600,000
#define U_ELEMS    (NUM_USERS * EMB) // 6,400,000
#define I_ELEMS    (NUM_ITEMS * EMB) // 3,200,000

#define RPB 256                       // rows per bucket (2^8: row>>8, row&255)
#define NB  ((N_NODES + RPB - 1) / RPB)   // 586 buckets
#define EPB 8192                      // edges staged per bin block

typedef __hip_bfloat16 bf16;

// flag bit0: float arrays are bf16 (else fp32). bit1: edge_index int64 (else int32).
__global__ void detect_kernel(const unsigned short* __restrict__ u16,
                              const int* __restrict__ ei32,
                              int* __restrict__ flag,
                              int* __restrict__ bucket_cnt)
{
    __shared__ int s_fp32, s_i32;
    if (threadIdx.x == 0) { s_fp32 = 0; s_i32 = 0; }
    __syncthreads();
    int t = threadIdx.x;
    for (int i = t; i < NB + 1; i += 256) bucket_cnt[i] = 0;
    unsigned short u = u16[t];
    int e = (u >> 7) & 0xFF;
    if (e >= 0xC0) atomicOr(&s_fp32, 1);
    if (t < 64 && ei32[2 * t + 1] != 0) atomicOr(&s_i32, 1);
    __syncthreads();
    if (t == 0) {
        int f = 0;
        if (!s_fp32) f |= 1;
        if (!s_i32)  f |= 2;
        *flag = f;
    }
}

__device__ __forceinline__ int load_row(const int* ei32, int f, size_t e) {
    return (f & 2) ? ei32[2 * e] : ei32[e];
}
__device__ __forceinline__ int load_col(const int* ei32, int f, size_t e) {
    return (f & 2) ? ei32[2 * ((size_t)N_EDGES + e)] : ei32[(size_t)N_EDGES + e];
}
__device__ __forceinline__ float load_w(const void* ew, int f, size_t e) {
    return (f & 1) ? __bfloat162float(((const bf16*)ew)[e]) : ((const float*)ew)[e];
}

// ---------- vectorized init: A + passthrough only (ACC fused into hop1) ----------
__global__ void init_vec_kernel(const void* __restrict__ users,
                                const void* __restrict__ items,
                                void* __restrict__ out,
                                void* __restrict__ A,
                                const int* __restrict__ flag)
{
    int g = blockIdx.x * blockDim.x + threadIdx.x;   // NODE_ELEMS/4 threads
    if (g >= NODE_ELEMS / 4) return;
    int g4 = g * 4;
    const bool isb = ((*flag) & 1);
    if (isb) {
        uint2 v;
        if (g4 < U_ELEMS) {
            v = ((const uint2*)users)[g];
            ((uint2*)((bf16*)out + U_ELEMS))[g] = v;
        } else {
            int ii = g - U_ELEMS / 4;
            v = ((const uint2*)items)[ii];
            ((uint2*)((bf16*)out + 2 * (size_t)U_ELEMS + I_ELEMS))[ii] = v;
        }
        ((uint2*)A)[g] = v;            // A stored bf16
    } else {
        float4 v;
        if (g4 < U_ELEMS) {
            v = ((const float4*)users)[g];
            ((float4*)((float*)out + U_ELEMS))[g] = v;
        } else {
            int ii = g - U_ELEMS / 4;
            v = ((const float4*)items)[ii];
            ((float4*)((float*)out + 2 * (size_t)U_ELEMS + I_ELEMS))[ii] = v;
        }
        ((float4*)A)[g] = v;           // A stored fp32
    }
}

// ---------- binned CSR build ----------

__global__ void bucket_hist_kernel(const int* __restrict__ ei32,
                                   int* __restrict__ bucket_cnt,
                                   const int* __restrict__ flag)
{
    __shared__ int h[NB];
    for (int i = threadIdx.x; i < NB; i += blockDim.x) h[i] = 0;
    __syncthreads();
    const int f = *flag;
    const size_t stride = (size_t)gridDim.x * blockDim.x;
    for (size_t e = (size_t)blockIdx.x * blockDim.x + threadIdx.x; e < N_EDGES; e += stride)
        atomicAdd(&h[load_row(ei32, f, e) >> 8], 1);
    __syncthreads();
    for (int i = threadIdx.x; i < NB; i += blockDim.x)
        if (h[i]) atomicAdd(&bucket_cnt[i], h[i]);
}

__global__ void bucket_scan_kernel(const int* __restrict__ bucket_cnt,
                                   int* __restrict__ bucket_base,
                                   int* __restrict__ bucket_off)
{
    __shared__ int ls[16];
    const int t = threadIdx.x;           // 1024 threads, NB <= 1024
    const int lane = t & 63, wv = t >> 6;
    int x = (t < NB) ? bucket_cnt[t] : 0;
    int v = x;
    #pragma unroll
    for (int d = 1; d < 64; d <<= 1) { int y = __shfl_up(v, d, 64); if (lane >= d) v += y; }
    if (lane == 63) ls[wv] = v;
    __syncthreads();
    if (wv == 0 && lane < 16) {
        int s = ls[lane];
        #pragma unroll
        for (int d = 1; d < 16; d <<= 1) { int y = __shfl_up(s, d, 64); if (lane >= d) s += y; }
        ls[lane] = s;
    }
    __syncthreads();
    int waveoff = wv ? ls[wv - 1] : 0;
    int excl = waveoff + v - x;
    if (t < NB) { bucket_base[t] = excl; bucket_off[t] = excl; }
    if (t == 0) bucket_base[NB] = ls[15];   // == N_EDGES
}

// stage 8192 edges in LDS, rank by bucket, write bucket-contiguous runs.
__global__ __launch_bounds__(1024) void bin_kernel(const int* __restrict__ ei32,
                                                   const void* __restrict__ ew,
                                                   int* __restrict__ bucket_off,
                                                   int2* __restrict__ rec,
                                                   const int* __restrict__ flag)
{
    __shared__ int2 stage[EPB];            // 64 KB
    __shared__ unsigned short bof[EPB];    // 16 KB
    __shared__ int hist[NB], excl0[NB], rank_[NB], gbase[NB];
    __shared__ int ls[16];
    const int t = threadIdx.x;
    const size_t base_e = (size_t)blockIdx.x * EPB;
    const int cnt = (int)(((base_e + EPB) <= N_EDGES) ? EPB : (N_EDGES - base_e));
    for (int i = t; i < NB; i += 1024) hist[i] = 0;
    __syncthreads();
    const int f = *flag;
    int  mybkt[8];
    int2 myrec[8];
    #pragma unroll
    for (int k = 0; k < 8; ++k) {
        int idx = k * 1024 + t;
        if (idx < cnt) {
            size_t e = base_e + idx;
            int row = load_row(ei32, f, e);
            int col = load_col(ei32, f, e);
            float w = load_w(ew, f, e);
            mybkt[k] = row >> 8;
            myrec[k] = make_int2(col | ((row & 255) << 18), __float_as_int(w));
            atomicAdd(&hist[mybkt[k]], 1);
        } else mybkt[k] = -1;
    }
    __syncthreads();
    {   // scan hist[0..NB) -> excl0, rank_
        const int lane = t & 63, wv = t >> 6;
        int x = (t < NB) ? hist[t] : 0;
        int v = x;
        #pragma unroll
        for (int d = 1; d < 64; d <<= 1) { int y = __shfl_up(v, d, 64); if (lane >= d) v += y; }
        if (lane == 63) ls[wv] = v;
        __syncthreads();
        if (wv == 0 && lane < 16) {
            int s = ls[lane];
            #pragma unroll
            for (int d = 1; d < 16; d <<= 1) { int y = __shfl_up(s, d, 64); if (lane >= d) s += y; }
            ls[lane] = s;
        }
        __syncthreads();
        int waveoff = wv ? ls[wv - 1] : 0;
        int excl = waveoff + v - x;
        if (t < NB) { excl0[t] = excl; rank_[t] = excl; }
    }
    __syncthreads();
    if (t < NB && hist[t] > 0) gbase[t] = atomicAdd(&bucket_off[t], hist[t]);
    else if (t < NB)           gbase[t] = 0;
    #pragma unroll
    for (int k = 0; k < 8; ++k) {
        if (mybkt[k] >= 0) {
            int p = atomicAdd(&rank_[mybkt[k]], 1);
            stage[p] = myrec[k];
            bof[p]   = (unsigned short)mybkt[k];
        }
    }
    __syncthreads();
    for (int s = t; s < cnt; s += 1024) {
        int b = bof[s];
        rec[gbase[b] + (s - excl0[b])] = stage[s];   // coalesced runs per bucket
    }
}

// one block per bucket: local row hist + scan -> rowptr; scatter csr within
// a 16KB L2-resident window (sector-dense writes, single XCD).
__global__ void local_fill_kernel(const int* __restrict__ bucket_base,
                                  const int2* __restrict__ rec,
                                  int* __restrict__ csr_col,
                                  float* __restrict__ csr_w,
                                  int* __restrict__ rowptr)
{
    __shared__ int hist[RPB], off[RPB], ls[4];
    const int b = blockIdx.x, t = threadIdx.x;      // 256 threads
    const int lo = bucket_base[b], hi = bucket_base[b + 1];
    const int rows = (N_NODES - b * RPB < RPB) ? (N_NODES - b * RPB) : RPB;
    hist[t] = 0;
    __syncthreads();
    for (int s = lo + t; s < hi; s += 256)
        atomicAdd(&hist[rec[s].x >> 18], 1);
    __syncthreads();
    const int lane = t & 63, wv = t >> 6;
    int x = hist[t];
    int v = x;
    #pragma unroll
    for (int d = 1; d < 64; d <<= 1) { int y = __shfl_up(v, d, 64); if (lane >= d) v += y; }
    if (lane == 63) ls[wv] = v;
    __syncthreads();
    if (wv == 0 && lane < 4) {
        int s = ls[lane];
        #pragma unroll
        for (int d = 1; d < 4; d <<= 1) { int y = __shfl_up(s, d, 64); if (lane >= d) s += y; }
        ls[lane] = s;
    }
    __syncthreads();
    int waveoff = wv ? ls[wv - 1] : 0;
    int excl = waveoff + v - x;
    if (t < rows) rowptr[b * RPB + t] = lo + excl;
    off[t] = lo + excl;
    if (b == NB - 1 && t == 0) rowptr[N_NODES] = N_EDGES;
    __syncthreads();
    for (int s = lo + t; s < hi; s += 256) {
        int2 r = rec[s];
        int rl = r.x >> 18;
        int pos = atomicAdd(&off[rl], 1);
        csr_col[pos] = r.x & 0x3FFFF;
        csr_w[pos]   = __int_as_float(r.y);
    }
}

// ---------- gather hop: wave per row, lane = emb dim, unroll 8 ----------
// FIRST: acc = emb0 + a (ACC never pre-initialized). LAST: out = (acc+a)/4.

template <bool FIRST, bool LAST>
__global__ void hop_kernel(const int* __restrict__ rowptr,
                           const int* __restrict__ csr_col,
                           const float* __restrict__ csr_w,
                           const void* __restrict__ prev,
                           void* __restrict__ next,
                           float* __restrict__ acc,
                           void* __restrict__ out,
                           const int* __restrict__ flag)
{
    int row  = blockIdx.x * (blockDim.x >> 6) + (threadIdx.x >> 6);
    int lane = threadIdx.x & 63;
    if (row >= N_NODES) return;
    const bool isb = ((*flag) & 1);
    int s = rowptr[row], e = rowptr[row + 1];
    float a0 = 0.f, a1 = 0.f, a2 = 0.f, a3 = 0.f;
    int k = s;
    if (isb) {
        const bf16* p = (const bf16*)prev;
        for (; k + 7 < e; k += 8) {
            int   c0 = csr_col[k],   c1 = csr_col[k+1], c2 = csr_col[k+2], c3 = csr_col[k+3];
            int   c4 = csr_col[k+4], c5 = csr_col[k+5], c6 = csr_col[k+6], c7 = csr_col[k+7];
            float w0 = csr_w[k],   w1 = csr_w[k+1], w2 = csr_w[k+2], w3 = csr_w[k+3];
            float w4 = csr_w[k+4], w5 = csr_w[k+5], w6 = csr_w[k+6], w7 = csr_w[k+7];
            float v0 = __bfloat162float(p[(size_t)c0 * EMB + lane]);
            float v1 = __bfloat162float(p[(size_t)c1 * EMB + lane]);
            float v2 = __bfloat162float(p[(size_t)c2 * EMB + lane]);
            float v3 = __bfloat162float(p[(size_t)c3 * EMB + lane]);
            float v4 = __bfloat162float(p[(size_t)c4 * EMB + lane]);
            float v5 = __bfloat162float(p[(size_t)c5 * EMB + lane]);
            float v6 = __bfloat162float(p[(size_t)c6 * EMB + lane]);
            float v7 = __bfloat162float(p[(size_t)c7 * EMB + lane]);
            a0 += w0 * v0; a1 += w1 * v1; a2 += w2 * v2; a3 += w3 * v3;
            a0 += w4 * v4; a1 += w5 * v5; a2 += w6 * v6; a3 += w7 * v7;
        }
        for (; k < e; ++k)
            a0 += csr_w[k] * __bfloat162float(p[(size_t)csr_col[k] * EMB + lane]);
    } else {
        const float* p = (const float*)prev;
        for (; k + 7 < e; k += 8) {
            int   c0 = csr_col[k],   c1 = csr_col[k+1], c2 = csr_col[k+2], c3 = csr_col[k+3];
            int   c4 = csr_col[k+4], c5 = csr_col[k+5], c6 = csr_col[k+6], c7 = csr_col[k+7];
            float w0 = csr_w[k],   w1 = csr_w[k+1], w2 = csr_w[k+2], w3 = csr_w[k+3];
            float w4 = csr_w[k+4], w5 = csr_w[k+5], w6 = csr_w[k+6], w7 = csr_w[k+7];
            float v0 = p[(size_t)c0 * EMB + lane];
            float v1 = p[(size_t)c1 * EMB + lane];
            float v2 = p[(size_t)c2 * EMB + lane];
            float v3 = p[(size_t)c3 * EMB + lane];
            float v4 = p[(size_t)c4 * EMB + lane];
            float v5 = p[(size_t)c5 * EMB + lane];
            float v6 = p[(size_t)c6 * EMB + lane];
            float v7 = p[(size_t)c7 * EMB + lane];
            a0 += w0 * v0; a1 += w1 * v1; a2 += w2 * v2; a3 += w3 * v3;
            a0 += w4 * v4; a1 += w5 * v5; a2 += w6 * v6; a3 += w7 * v7;
        }
        for (; k < e; ++k)
            a0 += csr_w[k] * p[(size_t)csr_col[k] * EMB + lane];
    }
    float a = (a0 + a1) + (a2 + a3);
    size_t o = (size_t)row * EMB + lane;
    if (LAST) {
        float v = (acc[o] + a) * 0.25f;
        size_t oo = (row < NUM_USERS) ? o : o + (size_t)U_ELEMS;
        if (isb) ((bf16*)out)[oo]  = __float2bfloat16(v);
        else     ((float*)out)[oo] = v;
    } else {
        if (isb) ((bf16*)next)[o] = __float2bfloat16(a);
        else     ((float*)next)[o] = a;
        if (FIRST) {
            float e0 = isb ? __bfloat162float(((const bf16*)prev)[o]) : ((const float*)prev)[o];
            acc[o] = e0 + a;
        } else {
            acc[o] += a;
        }
    }
}

// ---------- R3 atomic fallback ----------

__global__ void init_kernel(const void* __restrict__ users,
                            const void* __restrict__ items,
                            void* __restrict__ out,
                            float* __restrict__ A,
                            float* __restrict__ B,
                            float* __restrict__ ACC,
                            const int* __restrict__ flag)
{
    int gid = blockIdx.x * blockDim.x + threadIdx.x;
    if (gid >= NODE_ELEMS) return;
    const bool isb = ((*flag) & 1);
    float v;
    if (gid < U_ELEMS) {
        if (isb) { bf16 b = ((const bf16*)users)[gid]; v = __bfloat162float(b); ((bf16*)out)[U_ELEMS + gid] = b; }
        else     { float fv = ((const float*)users)[gid]; v = fv; ((float*)out)[U_ELEMS + gid] = fv; }
    } else {
        int ii = gid - U_ELEMS;
        if (isb) { bf16 b = ((const bf16*)items)[ii]; v = __bfloat162float(b); ((bf16*)out)[2 * U_ELEMS + I_ELEMS + ii] = b; }
        else     { float fv = ((const float*)items)[ii]; v = fv; ((float*)out)[2 * U_ELEMS + I_ELEMS + ii] = fv; }
    }
    A[gid]   = v;
    B[gid]   = 0.0f;
    ACC[gid] = v;
}

__global__ void finalize_kernel(const float* __restrict__ acc,
                                void* __restrict__ out,
                                const int* __restrict__ flag)
{
    int gid = blockIdx.x * blockDim.x + threadIdx.x;
    if (gid >= NODE_ELEMS) return;
    const bool isb = ((*flag) & 1);
    float v = acc[gid] * 0.25f;
    size_t o = (gid < U_ELEMS) ? (size_t)gid : (size_t)(2 * U_ELEMS + (gid - U_ELEMS));
    if (isb) ((bf16*)out)[o]  = __float2bfloat16(v);
    else     ((float*)out)[o] = v;
}

__global__ void scatter_kernel(const int* __restrict__ ei32,
                               const void* __restrict__ ew,
                               const float* __restrict__ prev,
                               float* __restrict__ next,
                               const int* __restrict__ flag)
{
    int gid = blockIdx.x * blockDim.x + threadIdx.x;
    if (gid >= N_EDGES * 16) return;
    const int f = *flag;
    int e = gid >> 4;
    int j = (gid & 15) << 2;
    int row = load_row(ei32, f, e);
    int col = load_col(ei32, f, e);
    float w = load_w(ew, f, e);
    const float4 v = *reinterpret_cast<const float4*>(prev + (size_t)col * EMB + j);
    float* dst = next + (size_t)row * EMB + j;
    unsafeAtomicAdd(dst + 0, w * v.x);
    unsafeAtomicAdd(dst + 1, w * v.y);
    unsafeAtomicAdd(dst + 2, w * v.z);
    unsafeAtomicAdd(dst + 3, w * v.w);
}

__global__ void accum_zero_kernel(float* __restrict__ acc,
                                  const float* __restrict__ next,
                                  float* __restrict__ prevz)
{
    int gid = blockIdx.x * blockDim.x + threadIdx.x;
    if (gid >= NODE_ELEMS) return;
    acc[gid] += next[gid];
    prevz[gid] = 0.0f;
}

__global__ void sentinel_kernel(unsigned int* __restrict__ out, int nwords)
{
    int gid = blockIdx.x * blockDim.x + threadIdx.x;
    if (gid < nwords) out[gid] = 0x447A447Au;
}

extern "C" void kernel_launch(void* const* d_in, const int* in_sizes, int n_in,
                              void* d_out, int out_size, void* d_ws, size_t ws_size,
                              hipStream_t stream)
{
    const void* users = d_in[0];
    const void* items = d_in[1];
    const int*  ei32  = (const int*)d_in[2];
    const void* ew    = d_in[3];

    char* wsb  = (char*)d_ws;
    int*  flag = (int*)wsb;
    float* A   = (float*)(wsb + 256);              // fp32-sized; holds bf16 in CSR path
    float* B   = A + (size_t)NODE_ELEMS;           // hop ping buffer; aliases rec
    float* ACC = B + (size_t)NODE_ELEMS;
    char* p    = (char*)(ACC + (size_t)NODE_ELEMS);
    int*  rowptr      = (int*)p;  p += (N_NODES + 4) * sizeof(int);
    int*  bucket_cnt  = (int*)p;  p += (NB + 2) * sizeof(int);
    int*  bucket_base = (int*)p;  p += (NB + 2) * sizeof(int);
    int*  bucket_off  = (int*)p;  p += (NB + 2) * sizeof(int);
    int*  csr_col     = (int*)p;  p += (size_t)N_EDGES * sizeof(int);
    float* csr_w      = (float*)p; p += (size_t)N_EDGES * sizeof(float);
    int2* rec         = (int2*)B;                  // alias: dead before hop1 writes B

    const size_t need_csr    = (size_t)(p - wsb);                  // ~154.4 MB
    const size_t need_atomic = 256 + 3 * (size_t)NODE_ELEMS * sizeof(float);
    const int BLK = 256;
    const int node_blocks = (NODE_ELEMS + BLK - 1) / BLK;
    const int vec_blocks  = (NODE_ELEMS / 4 + BLK - 1) / BLK;
    const int row_blocks  = (N_NODES + 3) / 4;       // 4 rows (waves) per block
    const int bin_blocks  = (N_EDGES + EPB - 1) / EPB;   // 586

    if (ws_size >= need_csr) {
        detect_kernel<<<1, BLK, 0, stream>>>((const unsigned short*)users, ei32, flag, bucket_cnt);
        init_vec_kernel<<<vec_blocks, BLK, 0, stream>>>(users, items, d_out, A, flag);
        bucket_hist_kernel<<<1024, BLK, 0, stream>>>(ei32, bucket_cnt, flag);
        bucket_scan_kernel<<<1, 1024, 0, stream>>>(bucket_cnt, bucket_base, bucket_off);
        bin_kernel<<<bin_blocks, 1024, 0, stream>>>(ei32, ew, bucket_off, rec, flag);
        local_fill_kernel<<<NB, RPB, 0, stream>>>(bucket_base, rec, csr_col, csr_w, rowptr);

        hop_kernel<true,  false><<<row_blocks, BLK, 0, stream>>>(rowptr, csr_col, csr_w, A, B, ACC, d_out, flag);
        hop_kernel<false, false><<<row_blocks, BLK, 0, stream>>>(rowptr, csr_col, csr_w, B, A, ACC, d_out, flag);
        hop_kernel<false, true ><<<row_blocks, BLK, 0, stream>>>(rowptr, csr_col, csr_w, A, B, ACC, d_out, flag);
    } else if (ws_size >= need_atomic) {
        const int sedge_blocks = (N_EDGES * 16 + BLK - 1) / BLK;
        detect_kernel<<<1, BLK, 0, stream>>>((const unsigned short*)users, ei32, flag, bucket_cnt);
        init_kernel<<<node_blocks, BLK, 0, stream>>>(users, items, d_out, A, B, ACC, flag);
        float* prev = A;
        float* nxt  = B;
        for (int h = 0; h < 3; ++h) {
            scatter_kernel<<<sedge_blocks, BLK, 0, stream>>>(ei32, ew, prev, nxt, flag);
            accum_zero_kernel<<<node_blocks, BLK, 0, stream>>>(ACC, nxt, prev);
            float* t = prev; prev = nxt; nxt = t;
        }
        finalize_kernel<<<node_blocks, BLK, 0, stream>>>(ACC, d_out, flag);
    } else {
        int nwords = out_size / 2;
        sentinel_kernel<<<(nwords + BLK - 1) / BLK, BLK, 0, stream>>>((unsigned int*)d_out, nwords);
    }
}